// Round 1
// baseline (29.268 us; speedup 1.0000x reference)
//
#include <hip/hip_runtime.h>

// Problem constants (from reference setup_inputs): B=8, Hc=88, Wc=288, k=4
// Output: (B, 9, H=352, W=1152) fp32, out[b,p,h,w] with p = 3*ih_idx + iw_idx,
//   h_shift = 4*(ih_idx-1), w_shift = 4*(iw_idx-1)
//   row = clip(h/4 + (ih_idx-1), 0, Hc-1), col = clip(w/4 + (iw_idx-1), 0, Wc-1)
//   n_c = plane_eq[b,c,row,col]
//   u = ((w%4) - 1.5)/4, v = ((h%4) - 1.5)/4
//   den = n0*(u - h_shift) + n1*(v - w_shift) + n2 ; out = n3/den
// Clamping note: for w in a 4-aligned group, clip(w + w_shift)/4 ==
// clip(w/4 + w_shift/4, 0, Wc-1) for all 4 elements (edge clamps collapse to
// column 0 / Wc-1), so the whole float4 shares one coefficient quadruple.

constexpr int Bc   = 8;
constexpr int Hc   = 88;
constexpr int Wc   = 288;
constexpr int K    = 4;
constexpr int H    = Hc * K;        // 352
constexpr int W    = Wc * K;        // 1152
constexpr int W4   = W / 4;         // 288
constexpr int HcWc = Hc * Wc;       // 25344

__global__ __launch_bounds__(256)
void lpg_kernel(const float* __restrict__ pe, float* __restrict__ out, int total)
{
    int tid = blockIdx.x * blockDim.x + threadIdx.x;
    if (tid >= total) return;

    // tid -> (b, p, h, wb)
    int wb = tid % W4;
    int t1 = tid / W4;
    int h  = t1 % H;
    int t2 = t1 / H;
    int p  = t2 % 9;
    int b  = t2 / 9;

    int ihs = p / 3 - 1;           // -1, 0, 1  (h_shift / k)
    int iws = p % 3 - 1;           // -1, 0, 1  (w_shift / k)

    int   hb = h >> 2;
    float v  = (float)(h & 3) * 0.25f - 0.375f;   // ((h%4) - 1.5)/4

    int row = min(max(hb + ihs, 0), Hc - 1);
    int col = min(max(wb + iws, 0), Wc - 1);

    const float* basep = pe + (size_t)b * (4 * HcWc) + (size_t)row * Wc + col;
    float n0 = basep[0 * HcWc];
    float n1 = basep[1 * HcWc];
    float n2 = basep[2 * HcWc];
    float n3 = basep[3 * HcWc];

    float hs = (float)(K * ihs);   // h_shift
    float ws = (float)(K * iws);   // w_shift

    float a = fmaf(n1, v - ws, n2);

    float4 o;
    o.x = n3 / fmaf(n0, -0.375f - hs, a);
    o.y = n3 / fmaf(n0, -0.125f - hs, a);
    o.z = n3 / fmaf(n0,  0.125f - hs, a);
    o.w = n3 / fmaf(n0,  0.375f - hs, a);

    reinterpret_cast<float4*>(out)[tid] = o;
}

extern "C" void kernel_launch(void* const* d_in, const int* in_sizes, int n_in,
                              void* d_out, int out_size, void* d_ws, size_t ws_size,
                              hipStream_t stream)
{
    const float* pe  = (const float*)d_in[0];
    float*       out = (float*)d_out;

    int total = out_size / 4;                 // one float4 per thread
    dim3 block(256);
    dim3 grid((total + 255) / 256);           // 28512 blocks exactly
    lpg_kernel<<<grid, block, 0, stream>>>(pe, out, total);
}

// Round 2
// 25.494 us; speedup vs baseline: 1.1480x; 1.1480x over previous
//
#include <hip/hip_runtime.h>

// LPG: B=8, Hc=88, Wc=288, k=4 -> out (8, 9, 352, 1152) fp32 (~116.8 MB).
// out[b,p,h,w] = n3 / (n0*(u - hs) + n1*(v - ws) + n2)
//   hs = 4*(p/3 - 1), ws = 4*(p%3 - 1)
//   n_c = pe[b, c, clip(h/4 + p/3-1, 0, Hc-1), clip(w/4 + p%3-1, 0, Wc-1)]
//   u = ((w%4) - 1.5)/4, v = ((h%4) - 1.5)/4   (phases from UNclipped h,w)
// One thread owns a 4x4 output block (fixed b,p,hb,wb): the coefficient
// quadruple is shared by all 16 outputs (clamps collapse uniformly on the
// whole group), so per thread: 4 loads, 4 float4 stores to rows 4*hb..4*hb+3.
// n3/den uses v_rcp_f32 (~1 ulp) — absmax threshold is 60.8, error ~1e-6.

constexpr int Hc   = 88;
constexpr int Wc   = 288;
constexpr int H    = Hc * 4;        // 352
constexpr int W4   = Wc;            // W/4 = 288 float4-groups per row
constexpr int HcWc = Hc * Wc;       // 25344

__global__ __launch_bounds__(256)
void lpg_kernel(const float* __restrict__ pe, float* __restrict__ out, int total)
{
    int tid = blockIdx.x * blockDim.x + threadIdx.x;
    if (tid >= total) return;

    // tid -> (b, p, hb, wb)
    int wb = tid % W4;
    int q1 = tid / W4;
    int hb = q1 % Hc;
    int q2 = q1 / Hc;
    int p  = q2 % 9;
    int b  = q2 / 9;

    int ihs = p / 3 - 1;            // -1, 0, 1
    int iws = p % 3 - 1;            // -1, 0, 1

    int row = min(max(hb + ihs, 0), Hc - 1);
    int col = min(max(wb + iws, 0), Wc - 1);

    const float* bp = pe + (size_t)b * (4 * HcWc) + (size_t)row * Wc + col;
    float n0 = bp[0 * HcWc];
    float n1 = bp[1 * HcWc];
    float n2 = bp[2 * HcWc];
    float n3 = bp[3 * HcWc];

    float hs = (float)(4 * ihs);
    float ws = (float)(4 * iws);

    // u_j - hs, j = w%4 phase: (-0.375 - hs) + 0.25*j
    float u0 = -0.375f - hs;
    float tu0 = n0 * u0;
    float tu1 = n0 * (u0 + 0.25f);
    float tu2 = n0 * (u0 + 0.50f);
    float tu3 = n0 * (u0 + 0.75f);

    float4* out4 = reinterpret_cast<float4*>(out)
                 + ((size_t)(q2 * H + 4 * hb)) * W4 + wb;

    float v0 = -0.375f - ws;        // v_r - ws = v0 + 0.25*r
    #pragma unroll
    for (int r = 0; r < 4; ++r) {
        float a = fmaf(n1, v0 + 0.25f * (float)r, n2);
        float4 o;
        o.x = n3 * __builtin_amdgcn_rcpf(a + tu0);
        o.y = n3 * __builtin_amdgcn_rcpf(a + tu1);
        o.z = n3 * __builtin_amdgcn_rcpf(a + tu2);
        o.w = n3 * __builtin_amdgcn_rcpf(a + tu3);
        out4[(size_t)r * W4] = o;
    }
}

extern "C" void kernel_launch(void* const* d_in, const int* in_sizes, int n_in,
                              void* d_out, int out_size, void* d_ws, size_t ws_size,
                              hipStream_t stream)
{
    const float* pe  = (const float*)d_in[0];
    float*       out = (float*)d_out;

    int total = 8 * 9 * Hc * W4;              // 1,824,768 threads (4x4 block each)
    dim3 block(256);
    dim3 grid(total / 256);                   // 7128 blocks exactly
    lpg_kernel<<<grid, block, 0, stream>>>(pe, out, total);
}

// Round 3
// 24.742 us; speedup vs baseline: 1.1829x; 1.0304x over previous
//
#include <hip/hip_runtime.h>

// LPG: B=8, Hc=88, Wc=288, k=4 -> out (8, 9, 352, 1152) fp32 (~116.8 MB).
// out[b,p,h,w] = n3 / (n0*(u - hs) + n1*(v - ws) + n2)
//   hs = 4*(p/3 - 1), ws = 4*(p%3 - 1)
//   n_c = pe[b, c, clip(h/4 + p/3-1, 0, Hc-1), clip(w/4 + p%3-1, 0, Wc-1)]
//   u = ((w%4) - 1.5)/4, v = ((h%4) - 1.5)/4   (phases from UNclipped h,w)
//
// Structure: one thread owns a 4x4 output block (fixed b,p,hb,wb) — all 16
// outputs share one coefficient quadruple (clamps collapse uniformly on the
// group). grid.y = b0*9+p (wave-uniform decompose); each thread does the
// SAME tile for b0 and b0+4 (identical p/row/col/phases, just +16*HcWc coef
// offset and +36 output planes) -> 8 nt stores per thread, half the waves.
// n3/den via v_rcp_f32 (~1 ulp); absmax threshold 60.8, measured 0.0156.

constexpr int Hc    = 88;
constexpr int Wc    = 288;
constexpr int H     = Hc * 4;          // 352
constexpr int W4    = Wc;              // W/4 = 288 float4 per output row
constexpr int HcWc  = Hc * Wc;         // 25344
constexpr int PL4   = H * W4;          // 101376 float4 per output plane

typedef float f32x4 __attribute__((ext_vector_type(4)));

__global__ __launch_bounds__(256)
void lpg_kernel(const float* __restrict__ pe, float* __restrict__ out)
{
    int t  = blockIdx.x * 256 + threadIdx.x;   // [0, 25344) tile within plane
    int q2 = blockIdx.y;                       // b0*9 + p, b0 in [0,4)

    int hb = t / 288;                          // one magic-mul chain
    int wb = t - hb * 288;

    int p   = q2 % 9;                          // wave-uniform (scalar)
    int pd3 = p / 3;
    int ihs = pd3 - 1;                         // -1, 0, 1
    int iws = p - 3 * pd3 - 1;                 // -1, 0, 1

    int row = min(max(hb + ihs, 0), Hc - 1);
    int col = min(max(wb + iws, 0), Wc - 1);

    float hs = (float)(4 * ihs);
    float ws = (float)(4 * iws);
    float u0 = -0.375f - hs;                   // u_j - hs = u0 + 0.25*j
    float v0 = -0.375f - ws;                   // v_r - ws = v0 + 0.25*r

    const float* bp = pe + (size_t)(q2 / 9) * (4 * HcWc)
                         + (size_t)row * Wc + col;
    f32x4* o4 = reinterpret_cast<f32x4*>(out)
              + (size_t)q2 * PL4 + (size_t)(4 * hb) * W4 + wb;

    #pragma unroll
    for (int half = 0; half < 2; ++half) {     // b0, then b0+4
        float n0 = bp[0 * HcWc];
        float n1 = bp[1 * HcWc];
        float n2 = bp[2 * HcWc];
        float n3 = bp[3 * HcWc];

        float tu0 = n0 * u0;
        float tu1 = n0 * (u0 + 0.25f);
        float tu2 = n0 * (u0 + 0.50f);
        float tu3 = n0 * (u0 + 0.75f);

        #pragma unroll
        for (int r = 0; r < 4; ++r) {
            float a = fmaf(n1, v0 + 0.25f * (float)r, n2);
            f32x4 o;
            o.x = n3 * __builtin_amdgcn_rcpf(a + tu0);
            o.y = n3 * __builtin_amdgcn_rcpf(a + tu1);
            o.z = n3 * __builtin_amdgcn_rcpf(a + tu2);
            o.w = n3 * __builtin_amdgcn_rcpf(a + tu3);
            __builtin_nontemporal_store(o, o4 + (size_t)r * W4);
        }
        bp += (size_t)16 * HcWc;               // b += 4  (4 batches * 4 ch)
        o4 += (size_t)36 * PL4;                // +36 output planes
    }
}

extern "C" void kernel_launch(void* const* d_in, const int* in_sizes, int n_in,
                              void* d_out, int out_size, void* d_ws, size_t ws_size,
                              hipStream_t stream)
{
    const float* pe  = (const float*)d_in[0];
    float*       out = (float*)d_out;

    dim3 block(256);
    dim3 grid(HcWc / 256 /* 99 */, 36);        // 36 = 4 batches * 9 planes
    lpg_kernel<<<grid, block, 0, stream>>>(pe, out);
}